// Round 6
// baseline (77.682 us; speedup 1.0000x reference)
//
#include <hip/hip_runtime.h>

#define B 2
#define N 16384
#define NPOINT 4096
#define C 64
#define NSAMPLE 32

// Threshold exactly as the JAX/numpy reference sees it:
// float32(double(0.1)*double(0.1)) = 0.009999999776482582f
__device__ __forceinline__ float r2_thresh() { return (float)(0.1 * 0.1); }

// Load one 256-point block (4 x 64 lanes) of xyz into registers.
__device__ __forceinline__ void load_block(const float* __restrict__ xb, int base, int lane,
                                           float (&x)[4], float (&y)[4], float (&z)[4]) {
#pragma unroll
    for (int u = 0; u < 4; ++u) {
        const int i = base + u * 64 + lane;
        x[u] = xb[i * 3 + 0];
        y[u] = xb[i * 3 + 1];
        z[u] = xb[i * 3 + 2];
    }
}

// Process one 256-point block: distance test, ballot-rank write, count update.
__device__ __forceinline__ void process_block(const float (&x)[4], const float (&y)[4],
                                              const float (&z)[4], int base, int lane,
                                              unsigned long long lanemask_lt,
                                              float cx, float cy, float cz, float r2,
                                              int& cnt, int& first_idx,
                                              int* __restrict__ out) {
    unsigned long long m[4];
    bool inball[4];
#pragma unroll
    for (int u = 0; u < 4; ++u) {
        float d2;
        {
#pragma clang fp contract(off)
            float dx = x[u] - cx;
            float dy = y[u] - cy;
            float dz = z[u] - cz;
            d2 = dx * dx + dy * dy + dz * dz;  // matches numpy: no FMA contraction
        }
        inball[u] = d2 < r2;
        m[u] = __ballot(inball[u]);
    }
#pragma unroll
    for (int u = 0; u < 4; ++u) {
        if (inball[u]) {
            const int rank = __popcll(m[u] & lanemask_lt);
            const int pos = cnt + rank;
            if (pos < NSAMPLE) out[pos] = base + u * 64 + lane;
        }
        if (cnt == 0 && m[u] != 0ull) {
            first_idx = base + u * 64 + __builtin_ctzll(m[u]);
        }
        cnt += __popcll(m[u]);
    }
}

// ---------------- Kernel 1: ball query, one wave per query ----------------
// 2-deep software pipeline: load block k+1 while computing block k, so L2
// latency hides under the current block's VALU work. Static double buffers
// (A/B) keep everything in registers (no runtime-indexed arrays).
__global__ void __launch_bounds__(256) ball_query_kernel(
    const float* __restrict__ xyz,      // (B, N, 3)
    const float* __restrict__ new_xyz,  // (B, NPOINT, 3)
    int* __restrict__ idx_out)          // (B, NPOINT, NSAMPLE)
{
    const int gtid = blockIdx.x * blockDim.x + threadIdx.x;
    const int wave = gtid >> 6;
    const int lane = threadIdx.x & 63;
    if (wave >= B * NPOINT) return;

    const int b = wave / NPOINT;
    const int j = wave - b * NPOINT;

    const float cx = new_xyz[(b * NPOINT + j) * 3 + 0];
    const float cy = new_xyz[(b * NPOINT + j) * 3 + 1];
    const float cz = new_xyz[(b * NPOINT + j) * 3 + 2];

    const float* __restrict__ xb = xyz + (size_t)b * N * 3;
    int* __restrict__ out = idx_out + ((size_t)b * NPOINT + j) * NSAMPLE;

    const float r2 = r2_thresh();
    const unsigned long long lanemask_lt = (lane == 63) ? 0x7FFFFFFFFFFFFFFFull
                                                        : ((1ull << lane) - 1ull);

    int cnt = 0;        // wave-uniform (derived from ballot)
    int first_idx = 0;  // wave-uniform

    float xa[4], ya[4], za[4];  // buffer A
    float xc[4], yc[4], zc[4];  // buffer B

    load_block(xb, 0, lane, xa, ya, za);

    for (int base = 0; base < N; base += 512) {
        // base+256 <= 16128 < N always inside the loop
        load_block(xb, base + 256, lane, xc, yc, zc);
        process_block(xa, ya, za, base, lane, lanemask_lt, cx, cy, cz, r2,
                      cnt, first_idx, out);
        if (cnt >= NSAMPLE) break;

        if (base + 512 < N) load_block(xb, base + 512, lane, xa, ya, za);
        process_block(xc, yc, zc, base + 256, lane, lanemask_lt, cx, cy, cz, r2,
                      cnt, first_idx, out);
        if (cnt >= NSAMPLE) break;
    }

    if (cnt < NSAMPLE) {
        if (cnt == 0) first_idx = 0;
        for (int pos = cnt + lane; pos < NSAMPLE; pos += 64) out[pos] = first_idx;
    }
}

// ---------------- Kernel T: transpose features (B,C,N) -> (B,N,C) ----------------
__global__ void __launch_bounds__(256) transpose_kernel(
    const float* __restrict__ feat,  // (B, C, N)
    float* __restrict__ ft)          // (B, N, C)
{
    __shared__ float tile[64 * 65];
    const int b = blockIdx.y;
    const int n0 = blockIdx.x * 64;
    const int t = threadIdx.x;
    const int l = t & 63;
    const int w = t >> 6;

#pragma unroll
    for (int it = 0; it < 16; ++it) {
        const int c = it * 4 + w;
        tile[c * 65 + l] = feat[((size_t)b * C + c) * N + n0 + l];
    }
    __syncthreads();
#pragma unroll
    for (int it = 0; it < 16; ++it) {
        const int nn = it * 4 + w;
        ft[((size_t)b * N + n0 + nn) * C + l] = tile[l * 65 + nn];
    }
}

// ---------------- Kernel 2: grouping using transposed features ----------------
__global__ void __launch_bounds__(256) group2_kernel(
    const float* __restrict__ xyz,      // (B, N, 3)
    const float* __restrict__ new_xyz,  // (B, NPOINT, 3)
    const float* __restrict__ ft,       // (B, N, C) transposed features
    const int* __restrict__ idx_arr,    // (B, NPOINT, NSAMPLE)
    float* __restrict__ out)            // (B, 3+C, NPOINT, NSAMPLE)
{
    __shared__ int sidx[64];
    __shared__ float sf[64 * 65];   // [pair][channel], pad 65 -> conflict-free reads

    const int t = threadIdx.x;
    const int b = blockIdx.y;
    const int j0 = blockIdx.x * 2;

    if (t < 64) sidx[t] = idx_arr[((size_t)b * NPOINT + j0) * NSAMPLE + t];
    __syncthreads();

    // Phase 1: gather features. pair p <- 16 lanes, each lane one float4.
    {
        const int lane16 = t & 15;
        const int pq = t >> 4;  // 0..15
#pragma unroll
        for (int it = 0; it < 4; ++it) {
            const int p = it * 16 + pq;
            const int id = sidx[p];
            const float4 v = *(const float4*)(ft + ((size_t)b * N + id) * C + lane16 * 4);
            float* dst = sf + p * 65 + lane16 * 4;
            dst[0] = v.x; dst[1] = v.y; dst[2] = v.z; dst[3] = v.w;
        }
    }

    const size_t plane = (size_t)NPOINT * NSAMPLE;
    const size_t obase = (size_t)b * (3 + C) * plane + (size_t)j0 * NSAMPLE;

    // xyz part: pair index = t (threads 0..63)
    if (t < 64) {
        const int id = sidx[t];
        const int q = t >> 5;  // local query 0/1
        const size_t cb = ((size_t)b * NPOINT + j0 + q) * 3;
        const size_t pb = ((size_t)b * N + id) * 3;
        {
#pragma clang fp contract(off)
            out[obase + 0 * plane + t] = xyz[pb + 0] - new_xyz[cb + 0];
            out[obase + 1 * plane + t] = xyz[pb + 1] - new_xyz[cb + 1];
            out[obase + 2 * plane + t] = xyz[pb + 2] - new_xyz[cb + 2];
        }
    }
    __syncthreads();

    // Phase 2: per iteration, wave w writes channel c = it*4+w for all 64 pairs.
    const int l = t & 63;
    const int w = t >> 6;
#pragma unroll
    for (int it = 0; it < 16; ++it) {
        const int c = it * 4 + w;
        out[obase + (size_t)(3 + c) * plane + l] = sf[l * 65 + c];
    }
}

// ---------------- Fallback grouping (original, used if ws too small) ----------------
__global__ void __launch_bounds__(256) group_kernel(
    const float* __restrict__ xyz,
    const float* __restrict__ new_xyz,
    const float* __restrict__ feat,     // (B, C, N)
    const int* __restrict__ idx_arr,
    float* __restrict__ out)
{
    const int t = threadIdx.x;
    const int s = t & 31;
    const int jl = t >> 5;
    const int j = blockIdx.x * 8 + jl;
    const int b = blockIdx.y;

    const int id = idx_arr[((size_t)b * NPOINT + j) * NSAMPLE + s];

    const float px = xyz[((size_t)b * N + id) * 3 + 0] - new_xyz[((size_t)b * NPOINT + j) * 3 + 0];
    const float py = xyz[((size_t)b * N + id) * 3 + 1] - new_xyz[((size_t)b * NPOINT + j) * 3 + 1];
    const float pz = xyz[((size_t)b * N + id) * 3 + 2] - new_xyz[((size_t)b * NPOINT + j) * 3 + 2];

    const size_t plane = (size_t)NPOINT * NSAMPLE;
    const size_t obase = (size_t)b * (3 + C) * plane + (size_t)j * NSAMPLE + s;

    out[obase + 0 * plane] = px;
    out[obase + 1 * plane] = py;
    out[obase + 2 * plane] = pz;

    const float* __restrict__ fb = feat + (size_t)b * C * N;
#pragma unroll 8
    for (int c = 0; c < C; ++c) {
        out[obase + (size_t)(3 + c) * plane] = fb[(size_t)c * N + id];
    }
}

extern "C" void kernel_launch(void* const* d_in, const int* in_sizes, int n_in,
                              void* d_out, int out_size, void* d_ws, size_t ws_size,
                              hipStream_t stream) {
    const float* xyz     = (const float*)d_in[0];  // (B, N, 3)
    const float* new_xyz = (const float*)d_in[1];  // (B, NPOINT, 3)
    const float* feat    = (const float*)d_in[2];  // (B, C, N)
    float* out = (float*)d_out;

    const size_t idx_bytes = (size_t)B * NPOINT * NSAMPLE * sizeof(int);   // 1 MB
    const size_t ft_bytes  = (size_t)B * N * C * sizeof(float);            // 8.4 MB

    int* idx_ws = (int*)d_ws;
    float* ft = (float*)((char*)d_ws + idx_bytes);

    const bool use_transposed = (ws_size >= idx_bytes + ft_bytes);

    if (use_transposed) {
        dim3 tg(N / 64, B);
        transpose_kernel<<<tg, 256, 0, stream>>>(feat, ft);
    }

    {
        const int waves = B * NPOINT;
        const int blocks = (waves * 64) / 256;
        ball_query_kernel<<<blocks, 256, 0, stream>>>(xyz, new_xyz, idx_ws);
    }

    if (use_transposed) {
        dim3 grid(NPOINT / 2, B);
        group2_kernel<<<grid, 256, 0, stream>>>(xyz, new_xyz, ft, idx_ws, out);
    } else {
        dim3 grid(NPOINT / 8, B);
        group_kernel<<<grid, 256, 0, stream>>>(xyz, new_xyz, feat, idx_ws, out);
    }
}

// Round 7
// 57.391 us; speedup vs baseline: 1.3535x; 1.3535x over previous
//
#include <hip/hip_runtime.h>

#define B 2
#define N 16384
#define NPOINT 4096
#define C 64
#define NSAMPLE 32

#define NCELL 1000        // 10x10x10 grid, cell size 0.1 == radius
#define CELLW_STRIDE 1024 // work array stride per batch (counts -> cursors)
#define OFF_STRIDE 1056   // offsets stride per batch (1001 used)
#define CAP 192           // per-query candidate capacity (mean ~69, 10-sigma safe)

// Threshold exactly as the JAX/numpy reference sees it:
// float32(double(0.1)*double(0.1)) = 0.009999999776482582f
__device__ __forceinline__ float r2_thresh() { return (float)(0.1 * 0.1); }

__device__ __forceinline__ int clamp09(int v) { return v < 0 ? 0 : (v > 9 ? 9 : v); }

__device__ __forceinline__ int cell_of(float x, float y, float z) {
    const int ix = clamp09((int)floorf(x * 10.0f));
    const int iy = clamp09((int)floorf(y * 10.0f));
    const int iz = clamp09((int)floorf(z * 10.0f));
    return (ix * 10 + iy) * 10 + iz;
}

// ---------------- Grid build ----------------
__global__ void __launch_bounds__(256) grid_init_kernel(int* __restrict__ cellwork) {
    const int t = blockIdx.x * blockDim.x + threadIdx.x;
    if (t < B * CELLW_STRIDE) cellwork[t] = 0;
}

__global__ void __launch_bounds__(256) grid_hist_kernel(
    const float* __restrict__ xyz, int* __restrict__ cellwork) {
    const int i = blockIdx.x * blockDim.x + threadIdx.x;  // over B*N
    if (i >= B * N) return;
    const int b = i / N;
    const float x = xyz[(size_t)i * 3 + 0];
    const float y = xyz[(size_t)i * 3 + 1];
    const float z = xyz[(size_t)i * 3 + 2];
    atomicAdd(&cellwork[b * CELLW_STRIDE + cell_of(x, y, z)], 1);
}

// One block (1024 threads) per batch: exclusive scan of counts -> off[0..1000],
// and rewrite cellwork with the exclusive offsets (becomes the scatter cursors).
__global__ void __launch_bounds__(1024) grid_scan_kernel(
    int* __restrict__ cellwork, int* __restrict__ off) {
    __shared__ int s[1024];
    const int b = blockIdx.x;
    const int t = threadIdx.x;
    const int v = (t < NCELL) ? cellwork[b * CELLW_STRIDE + t] : 0;
    s[t] = v;
    __syncthreads();
#pragma unroll
    for (int d = 1; d < 1024; d <<= 1) {
        const int add = (t >= d) ? s[t - d] : 0;
        __syncthreads();
        s[t] += add;
        __syncthreads();
    }
    const int excl = s[t] - v;
    if (t <= NCELL) off[b * OFF_STRIDE + t] = excl;   // off[1000] = N (total)
    if (t < NCELL) cellwork[b * CELLW_STRIDE + t] = excl;  // cursor for scatter
}

__global__ void __launch_bounds__(256) grid_scatter_kernel(
    const float* __restrict__ xyz, int* __restrict__ cellwork,
    float4* __restrict__ binned) {
    const int i = blockIdx.x * blockDim.x + threadIdx.x;  // over B*N
    if (i >= B * N) return;
    const int b = i / N;
    const int p = i - b * N;
    const float x = xyz[(size_t)i * 3 + 0];
    const float y = xyz[(size_t)i * 3 + 1];
    const float z = xyz[(size_t)i * 3 + 2];
    const int c = cell_of(x, y, z);
    const int pos = atomicAdd(&cellwork[b * CELLW_STRIDE + c], 1);
    float4 v;
    v.x = x; v.y = y; v.z = z; v.w = __int_as_float(p);
    binned[(size_t)b * N + pos] = v;
}

// ---------------- exact linear-scan fallback (in-wave) ----------------
__device__ void linear_ball_fallback(const float* __restrict__ xb,
                                     float cx, float cy, float cz,
                                     int lane, unsigned long long lanemask_lt,
                                     int* __restrict__ out) {
    const float r2 = r2_thresh();
    int cnt = 0, first_idx = 0;
    for (int base = 0; base < N; base += 64) {
        const int i = base + lane;
        const float x = xb[i * 3 + 0];
        const float y = xb[i * 3 + 1];
        const float z = xb[i * 3 + 2];
        float d2;
        {
#pragma clang fp contract(off)
            float dx = x - cx;
            float dy = y - cy;
            float dz = z - cz;
            d2 = dx * dx + dy * dy + dz * dz;
        }
        const bool in = d2 < r2;
        const unsigned long long m = __ballot(in);
        if (in) {
            const int pos = cnt + __popcll(m & lanemask_lt);
            if (pos < NSAMPLE) out[pos] = i;
        }
        if (cnt == 0 && m != 0ull) first_idx = base + __builtin_ctzll(m);
        cnt += __popcll(m);
        if (cnt >= NSAMPLE) break;
    }
    if (cnt < NSAMPLE) {
        if (cnt == 0) first_idx = 0;
        for (int pos = cnt + lane; pos < NSAMPLE; pos += 64) out[pos] = first_idx;
    }
}

// ---------------- Kernel 1g: ball query via grid, one wave per query ----------------
// Scan <=27 neighbor cells (~443 pts avg vs 11.6k linear), collect in-ball
// candidate indices in LDS, then rank-select the 32 smallest indices (== first
// 32 in original order). Distances computed on bit-identical copies, contract off.
__global__ void __launch_bounds__(256) ball_query_grid_kernel(
    const float4* __restrict__ binned,   // (B, N) {x,y,z,idx}
    const int* __restrict__ off,         // (B, OFF_STRIDE) cell offsets, off[1000]=N
    const float* __restrict__ new_xyz,   // (B, NPOINT, 3)
    const float* __restrict__ xyz,       // (B, N, 3) for overflow fallback
    int* __restrict__ idx_out)           // (B, NPOINT, NSAMPLE)
{
    __shared__ int cand_s[4][CAP];
    const int lane = threadIdx.x & 63;
    const int wib = threadIdx.x >> 6;
    const int wave = (blockIdx.x * blockDim.x + threadIdx.x) >> 6;
    if (wave >= B * NPOINT) return;
    const int b = wave / NPOINT;

    const float cx = new_xyz[(size_t)wave * 3 + 0];
    const float cy = new_xyz[(size_t)wave * 3 + 1];
    const float cz = new_xyz[(size_t)wave * 3 + 2];

    int* __restrict__ cand = cand_s[wib];
    const float4* __restrict__ bb = binned + (size_t)b * N;
    const int* __restrict__ ob = off + b * OFF_STRIDE;
    int* __restrict__ out = idx_out + (size_t)wave * NSAMPLE;

    const float r2 = r2_thresh();
    const unsigned long long lanemask_lt = (lane == 63) ? 0x7FFFFFFFFFFFFFFFull
                                                        : ((1ull << lane) - 1ull);

    // Window from coordinates +-0.1001 (covers all FP boundary rounding; <=3 cells/axis)
    const int lox = max(0, (int)floorf((cx - 0.1001f) * 10.0f));
    const int hix = min(9, (int)floorf((cx + 0.1001f) * 10.0f));
    const int loy = max(0, (int)floorf((cy - 0.1001f) * 10.0f));
    const int hiy = min(9, (int)floorf((cy + 0.1001f) * 10.0f));
    const int loz = max(0, (int)floorf((cz - 0.1001f) * 10.0f));
    const int hiz = min(9, (int)floorf((cz + 0.1001f) * 10.0f));

    int K = 0;
    for (int ix = lox; ix <= hix; ++ix) {
        for (int iy = loy; iy <= hiy; ++iy) {
            const int rowc = (ix * 10 + iy) * 10;
            const int s0 = ob[rowc + loz];
            const int s1 = ob[rowc + hiz + 1];  // z cells contiguous -> one segment
            for (int cur = s0; cur < s1; cur += 64) {
                const int i = cur + lane;
                const bool valid = (i < s1);
                float4 pv;
                if (valid) pv = bb[i];
                else { pv.x = 1e9f; pv.y = 1e9f; pv.z = 1e9f; pv.w = 0.0f; }
                float d2;
                {
#pragma clang fp contract(off)
                    float dx = pv.x - cx;
                    float dy = pv.y - cy;
                    float dz = pv.z - cz;
                    d2 = dx * dx + dy * dy + dz * dz;
                }
                const bool in = valid && (d2 < r2);
                const unsigned long long m = __ballot(in);
                if (in) {
                    const int pos = K + __popcll(m & lanemask_lt);
                    if (pos < CAP) cand[pos] = __float_as_int(pv.w);
                }
                K += __popcll(m);
            }
        }
    }

    if (K > CAP) {  // pathological density: exact linear rescan (wave-uniform)
        linear_ball_fallback(xyz + (size_t)b * N * 3, cx, cy, cz, lane, lanemask_lt, out);
        return;
    }

    // Rank selection: rank(e) = #{candidates with smaller index}; indices unique.
    const int e0 = (lane < K) ? cand[lane] : 0x7FFFFFFF;
    const int e1 = (64 + lane < K) ? cand[64 + lane] : 0x7FFFFFFF;
    const int e2 = (128 + lane < K) ? cand[128 + lane] : 0x7FFFFFFF;
    int r0 = 0, r1 = 0, r2i = 0;
    if (K <= 64) {
        for (int k = 0; k < K; ++k) { const int v = cand[k]; r0 += (v < e0); }
    } else if (K <= 128) {
        for (int k = 0; k < K; ++k) { const int v = cand[k]; r0 += (v < e0); r1 += (v < e1); }
    } else {
        for (int k = 0; k < K; ++k) {
            const int v = cand[k];
            r0 += (v < e0); r1 += (v < e1); r2i += (v < e2);
        }
    }
    if (lane < K && r0 < NSAMPLE) out[r0] = e0;
    if (64 + lane < K && r1 < NSAMPLE) out[r1] = e1;
    if (128 + lane < K && r2i < NSAMPLE) out[r2i] = e2;

    if (K < NSAMPLE) {
        int mn = min(e0, min(e1, e2));
#pragma unroll
        for (int d = 32; d; d >>= 1) mn = min(mn, __shfl_xor(mn, d));
        const int fill = (K > 0) ? mn : 0;
        for (int pos = K + lane; pos < NSAMPLE; pos += 64) out[pos] = fill;
    }
}

// ---------------- Kernel 1: linear ball query (ws-too-small fallback) ----------------
__global__ void __launch_bounds__(256) ball_query_kernel(
    const float* __restrict__ xyz, const float* __restrict__ new_xyz,
    int* __restrict__ idx_out)
{
    const int wave = (blockIdx.x * blockDim.x + threadIdx.x) >> 6;
    const int lane = threadIdx.x & 63;
    if (wave >= B * NPOINT) return;
    const int b = wave / NPOINT;
    const float cx = new_xyz[(size_t)wave * 3 + 0];
    const float cy = new_xyz[(size_t)wave * 3 + 1];
    const float cz = new_xyz[(size_t)wave * 3 + 2];
    const unsigned long long lanemask_lt = (lane == 63) ? 0x7FFFFFFFFFFFFFFFull
                                                        : ((1ull << lane) - 1ull);
    linear_ball_fallback(xyz + (size_t)b * N * 3, cx, cy, cz, lane, lanemask_lt,
                         idx_out + (size_t)wave * NSAMPLE);
}

// ---------------- Kernel T: transpose features (B,C,N) -> (B,N,C) ----------------
__global__ void __launch_bounds__(256) transpose_kernel(
    const float* __restrict__ feat, float* __restrict__ ft) {
    __shared__ float tile[64 * 65];
    const int b = blockIdx.y;
    const int n0 = blockIdx.x * 64;
    const int t = threadIdx.x;
    const int l = t & 63;
    const int w = t >> 6;
#pragma unroll
    for (int it = 0; it < 16; ++it) {
        const int c = it * 4 + w;
        tile[c * 65 + l] = feat[((size_t)b * C + c) * N + n0 + l];
    }
    __syncthreads();
#pragma unroll
    for (int it = 0; it < 16; ++it) {
        const int nn = it * 4 + w;
        ft[((size_t)b * N + n0 + nn) * C + l] = tile[l * 65 + nn];
    }
}

// ---------------- Kernel 2: grouping using transposed features ----------------
__global__ void __launch_bounds__(256) group2_kernel(
    const float* __restrict__ xyz, const float* __restrict__ new_xyz,
    const float* __restrict__ ft, const int* __restrict__ idx_arr,
    float* __restrict__ out) {
    __shared__ int sidx[64];
    __shared__ float sf[64 * 65];

    const int t = threadIdx.x;
    const int b = blockIdx.y;
    const int j0 = blockIdx.x * 2;

    if (t < 64) sidx[t] = idx_arr[((size_t)b * NPOINT + j0) * NSAMPLE + t];
    __syncthreads();

    {
        const int lane16 = t & 15;
        const int pq = t >> 4;
#pragma unroll
        for (int it = 0; it < 4; ++it) {
            const int p = it * 16 + pq;
            const int id = sidx[p];
            const float4 v = *(const float4*)(ft + ((size_t)b * N + id) * C + lane16 * 4);
            float* dst = sf + p * 65 + lane16 * 4;
            dst[0] = v.x; dst[1] = v.y; dst[2] = v.z; dst[3] = v.w;
        }
    }

    const size_t plane = (size_t)NPOINT * NSAMPLE;
    const size_t obase = (size_t)b * (3 + C) * plane + (size_t)j0 * NSAMPLE;

    if (t < 64) {
        const int id = sidx[t];
        const int q = t >> 5;
        const size_t cb = ((size_t)b * NPOINT + j0 + q) * 3;
        const size_t pb = ((size_t)b * N + id) * 3;
        {
#pragma clang fp contract(off)
            out[obase + 0 * plane + t] = xyz[pb + 0] - new_xyz[cb + 0];
            out[obase + 1 * plane + t] = xyz[pb + 1] - new_xyz[cb + 1];
            out[obase + 2 * plane + t] = xyz[pb + 2] - new_xyz[cb + 2];
        }
    }
    __syncthreads();

    const int l = t & 63;
    const int w = t >> 6;
#pragma unroll
    for (int it = 0; it < 16; ++it) {
        const int c = it * 4 + w;
        out[obase + (size_t)(3 + c) * plane + l] = sf[l * 65 + c];
    }
}

// ---------------- Fallback grouping (ws too small for transpose) ----------------
__global__ void __launch_bounds__(256) group_kernel(
    const float* __restrict__ xyz, const float* __restrict__ new_xyz,
    const float* __restrict__ feat, const int* __restrict__ idx_arr,
    float* __restrict__ out) {
    const int t = threadIdx.x;
    const int s = t & 31;
    const int jl = t >> 5;
    const int j = blockIdx.x * 8 + jl;
    const int b = blockIdx.y;

    const int id = idx_arr[((size_t)b * NPOINT + j) * NSAMPLE + s];

    const float px = xyz[((size_t)b * N + id) * 3 + 0] - new_xyz[((size_t)b * NPOINT + j) * 3 + 0];
    const float py = xyz[((size_t)b * N + id) * 3 + 1] - new_xyz[((size_t)b * NPOINT + j) * 3 + 1];
    const float pz = xyz[((size_t)b * N + id) * 3 + 2] - new_xyz[((size_t)b * NPOINT + j) * 3 + 2];

    const size_t plane = (size_t)NPOINT * NSAMPLE;
    const size_t obase = (size_t)b * (3 + C) * plane + (size_t)j * NSAMPLE + s;

    out[obase + 0 * plane] = px;
    out[obase + 1 * plane] = py;
    out[obase + 2 * plane] = pz;

    const float* __restrict__ fb = feat + (size_t)b * C * N;
#pragma unroll 8
    for (int c = 0; c < C; ++c) {
        out[obase + (size_t)(3 + c) * plane] = fb[(size_t)c * N + id];
    }
}

extern "C" void kernel_launch(void* const* d_in, const int* in_sizes, int n_in,
                              void* d_out, int out_size, void* d_ws, size_t ws_size,
                              hipStream_t stream) {
    const float* xyz     = (const float*)d_in[0];  // (B, N, 3)
    const float* new_xyz = (const float*)d_in[1];  // (B, NPOINT, 3)
    const float* feat    = (const float*)d_in[2];  // (B, C, N)
    float* out = (float*)d_out;

    // Workspace layout
    const size_t idx_bytes    = (size_t)B * NPOINT * NSAMPLE * sizeof(int);  // 1,048,576
    const size_t ft_bytes     = (size_t)B * N * C * sizeof(float);           // 8,388,608
    const size_t binned_bytes = (size_t)B * N * sizeof(float4);              //   524,288
    const size_t off_bytes    = (size_t)B * OFF_STRIDE * sizeof(int);        //     8,448
    const size_t cellw_bytes  = (size_t)B * CELLW_STRIDE * sizeof(int);      //     8,192

    char* ws = (char*)d_ws;
    int*    idx_ws   = (int*)ws;
    float*  ft       = (float*)(ws + idx_bytes);
    float4* binned   = (float4*)(ws + idx_bytes + ft_bytes);
    int*    off      = (int*)(ws + idx_bytes + ft_bytes + binned_bytes);
    int*    cellwork = (int*)(ws + idx_bytes + ft_bytes + binned_bytes + off_bytes);

    const bool use_ft   = (ws_size >= idx_bytes + ft_bytes);
    const bool use_grid = (ws_size >= idx_bytes + ft_bytes + binned_bytes + off_bytes + cellw_bytes);

    if (use_ft) {
        dim3 tg(N / 64, B);
        transpose_kernel<<<tg, 256, 0, stream>>>(feat, ft);
    }

    if (use_grid) {
        grid_init_kernel<<<(B * CELLW_STRIDE + 255) / 256, 256, 0, stream>>>(cellwork);
        grid_hist_kernel<<<(B * N + 255) / 256, 256, 0, stream>>>(xyz, cellwork);
        grid_scan_kernel<<<B, 1024, 0, stream>>>(cellwork, off);
        grid_scatter_kernel<<<(B * N + 255) / 256, 256, 0, stream>>>(xyz, cellwork, binned);
        ball_query_grid_kernel<<<(B * NPOINT) / 4, 256, 0, stream>>>(
            binned, off, new_xyz, xyz, idx_ws);
    } else {
        ball_query_kernel<<<(B * NPOINT) / 4, 256, 0, stream>>>(xyz, new_xyz, idx_ws);
    }

    if (use_ft) {
        dim3 grid2(NPOINT / 2, B);
        group2_kernel<<<grid2, 256, 0, stream>>>(xyz, new_xyz, ft, idx_ws, out);
    } else {
        dim3 grid2(NPOINT / 8, B);
        group_kernel<<<grid2, 256, 0, stream>>>(xyz, new_xyz, feat, idx_ws, out);
    }
}

// Round 8
// 54.483 us; speedup vs baseline: 1.4258x; 1.0534x over previous
//
#include <hip/hip_runtime.h>

#define B 2
#define N 16384
#define NPOINT 4096
#define C 64
#define NSAMPLE 32

#define NCELL 1000        // 10x10x10 grid, cell size 0.1 == radius
#define CELLW_STRIDE 1024 // work array stride per batch
#define OFF_STRIDE 1056   // offsets stride per batch (1001 used)
#define CAP 192           // per-query candidate capacity (mean ~69)

// Threshold exactly as the JAX/numpy reference sees it:
// float32(double(0.1)*double(0.1)) = 0.009999999776482582f
__device__ __forceinline__ float r2_thresh() { return (float)(0.1 * 0.1); }

__device__ __forceinline__ int clamp09(int v) { return v < 0 ? 0 : (v > 9 ? 9 : v); }

__device__ __forceinline__ int cell_of(float x, float y, float z) {
    const int ix = clamp09((int)floorf(x * 10.0f));
    const int iy = clamp09((int)floorf(y * 10.0f));
    const int iz = clamp09((int)floorf(z * 10.0f));
    return (ix * 10 + iy) * 10 + iz;
}

// ---------------- Grid + query-sort build ----------------
__global__ void __launch_bounds__(256) grid_init_kernel(int* __restrict__ work) {
    const int t = blockIdx.x * blockDim.x + threadIdx.x;
    if (t < 2 * B * CELLW_STRIDE) work[t] = 0;  // cellwork then qwork (adjacent)
}

// Histogram points AND queries into per-batch cell counters.
__global__ void __launch_bounds__(256) grid_hist_kernel(
    const float* __restrict__ xyz, const float* __restrict__ new_xyz,
    int* __restrict__ cellwork, int* __restrict__ qwork) {
    const int i = blockIdx.x * blockDim.x + threadIdx.x;  // over B*(N+NPOINT)
    if (i < B * N) {
        const int b = i / N;
        const float x = xyz[(size_t)i * 3 + 0];
        const float y = xyz[(size_t)i * 3 + 1];
        const float z = xyz[(size_t)i * 3 + 2];
        atomicAdd(&cellwork[b * CELLW_STRIDE + cell_of(x, y, z)], 1);
    } else if (i < B * (N + NPOINT)) {
        const int qi = i - B * N;
        const int b = qi / NPOINT;
        const float x = new_xyz[(size_t)qi * 3 + 0];
        const float y = new_xyz[(size_t)qi * 3 + 1];
        const float z = new_xyz[(size_t)qi * 3 + 2];
        atomicAdd(&qwork[b * CELLW_STRIDE + cell_of(x, y, z)], 1);
    }
}

// 2B blocks: blocks [0,B) scan point counts -> off + scatter cursors;
// blocks [B,2B) scan query counts -> scatter cursors only.
__global__ void __launch_bounds__(1024) grid_scan_kernel(
    int* __restrict__ cellwork, int* __restrict__ qwork, int* __restrict__ off) {
    __shared__ int s[1024];
    const int blk = blockIdx.x;
    const int t = threadIdx.x;
    int* __restrict__ arr = (blk < B) ? (cellwork + blk * CELLW_STRIDE)
                                      : (qwork + (blk - B) * CELLW_STRIDE);
    const int v = (t < NCELL) ? arr[t] : 0;
    s[t] = v;
    __syncthreads();
#pragma unroll
    for (int d = 1; d < 1024; d <<= 1) {
        const int add = (t >= d) ? s[t - d] : 0;
        __syncthreads();
        s[t] += add;
        __syncthreads();
    }
    const int excl = s[t] - v;
    if (blk < B && t <= NCELL) off[blk * OFF_STRIDE + t] = excl;  // off[1000] = N
    if (t < NCELL) arr[t] = excl;  // cursors for scatter
}

// Scatter points into binned (float4 {x,y,z,idx}) AND queries into qperm.
__global__ void __launch_bounds__(256) grid_scatter_kernel(
    const float* __restrict__ xyz, const float* __restrict__ new_xyz,
    int* __restrict__ cellwork, int* __restrict__ qwork,
    float4* __restrict__ binned, int* __restrict__ qperm) {
    const int i = blockIdx.x * blockDim.x + threadIdx.x;
    if (i < B * N) {
        const int b = i / N;
        const int p = i - b * N;
        const float x = xyz[(size_t)i * 3 + 0];
        const float y = xyz[(size_t)i * 3 + 1];
        const float z = xyz[(size_t)i * 3 + 2];
        const int c = cell_of(x, y, z);
        const int pos = atomicAdd(&cellwork[b * CELLW_STRIDE + c], 1);
        float4 v;
        v.x = x; v.y = y; v.z = z; v.w = __int_as_float(p);
        binned[(size_t)b * N + pos] = v;
    } else if (i < B * (N + NPOINT)) {
        const int qi = i - B * N;
        const int b = qi / NPOINT;
        const int j = qi - b * NPOINT;
        const float x = new_xyz[(size_t)qi * 3 + 0];
        const float y = new_xyz[(size_t)qi * 3 + 1];
        const float z = new_xyz[(size_t)qi * 3 + 2];
        const int c = cell_of(x, y, z);
        const int pos = atomicAdd(&qwork[b * CELLW_STRIDE + c], 1);
        qperm[b * NPOINT + pos] = j;
    }
}

// ---------------- exact linear-scan fallback (in-wave) ----------------
__device__ void linear_ball_fallback(const float* __restrict__ xb,
                                     float cx, float cy, float cz,
                                     int lane, unsigned long long lanemask_lt,
                                     int* __restrict__ out) {
    const float r2 = r2_thresh();
    int cnt = 0, first_idx = 0;
    for (int base = 0; base < N; base += 64) {
        const int i = base + lane;
        const float x = xb[i * 3 + 0];
        const float y = xb[i * 3 + 1];
        const float z = xb[i * 3 + 2];
        float d2;
        {
#pragma clang fp contract(off)
            float dx = x - cx;
            float dy = y - cy;
            float dz = z - cz;
            d2 = dx * dx + dy * dy + dz * dz;
        }
        const bool in = d2 < r2;
        const unsigned long long m = __ballot(in);
        if (in) {
            const int pos = cnt + __popcll(m & lanemask_lt);
            if (pos < NSAMPLE) out[pos] = i;
        }
        if (cnt == 0 && m != 0ull) first_idx = base + __builtin_ctzll(m);
        cnt += __popcll(m);
        if (cnt >= NSAMPLE) break;
    }
    if (cnt < NSAMPLE) {
        if (cnt == 0) first_idx = 0;
        for (int pos = cnt + lane; pos < NSAMPLE; pos += 64) out[pos] = first_idx;
    }
}

// ---------------- Kernel 1g: ball query via grid, sorted queries ----------------
__global__ void __launch_bounds__(256) ball_query_grid_kernel(
    const float4* __restrict__ binned,   // (B, N) {x,y,z,idx}
    const int* __restrict__ off,         // (B, OFF_STRIDE)
    const float* __restrict__ new_xyz,   // (B, NPOINT, 3)
    const float* __restrict__ xyz,       // (B, N, 3) overflow fallback
    const int* __restrict__ qperm,       // (B, NPOINT) sorted -> original query
    int* __restrict__ idx_out)           // (B, NPOINT, NSAMPLE)
{
    __shared__ int cand_s[4][CAP];
    const int lane = threadIdx.x & 63;
    const int wib = threadIdx.x >> 6;
    const int wave = (blockIdx.x * blockDim.x + threadIdx.x) >> 6;  // sorted position
    if (wave >= B * NPOINT) return;
    const int b = wave / NPOINT;
    const int sp = wave - b * NPOINT;
    const int j = qperm[b * NPOINT + sp];   // original query index (broadcast load)

    const float cx = new_xyz[((size_t)b * NPOINT + j) * 3 + 0];
    const float cy = new_xyz[((size_t)b * NPOINT + j) * 3 + 1];
    const float cz = new_xyz[((size_t)b * NPOINT + j) * 3 + 2];

    int* __restrict__ cand = cand_s[wib];
    const float4* __restrict__ bb = binned + (size_t)b * N;
    const int* __restrict__ ob = off + b * OFF_STRIDE;
    int* __restrict__ out = idx_out + ((size_t)b * NPOINT + j) * NSAMPLE;

    const float r2 = r2_thresh();
    const unsigned long long lanemask_lt = (lane == 63) ? 0x7FFFFFFFFFFFFFFFull
                                                        : ((1ull << lane) - 1ull);

    const int lox = max(0, (int)floorf((cx - 0.1001f) * 10.0f));
    const int hix = min(9, (int)floorf((cx + 0.1001f) * 10.0f));
    const int loy = max(0, (int)floorf((cy - 0.1001f) * 10.0f));
    const int hiy = min(9, (int)floorf((cy + 0.1001f) * 10.0f));
    const int loz = max(0, (int)floorf((cz - 0.1001f) * 10.0f));
    const int hiz = min(9, (int)floorf((cz + 0.1001f) * 10.0f));

    int K = 0;
    for (int ix = lox; ix <= hix; ++ix) {
        for (int iy = loy; iy <= hiy; ++iy) {
            const int rowc = (ix * 10 + iy) * 10;
            const int s0 = ob[rowc + loz];
            const int s1 = ob[rowc + hiz + 1];
            for (int cur = s0; cur < s1; cur += 64) {
                const int i = cur + lane;
                const bool valid = (i < s1);
                float4 pv;
                if (valid) pv = bb[i];
                else { pv.x = 1e9f; pv.y = 1e9f; pv.z = 1e9f; pv.w = 0.0f; }
                float d2;
                {
#pragma clang fp contract(off)
                    float dx = pv.x - cx;
                    float dy = pv.y - cy;
                    float dz = pv.z - cz;
                    d2 = dx * dx + dy * dy + dz * dz;
                }
                const bool in = valid && (d2 < r2);
                const unsigned long long m = __ballot(in);
                if (in) {
                    const int pos = K + __popcll(m & lanemask_lt);
                    if (pos < CAP) cand[pos] = __float_as_int(pv.w);
                }
                K += __popcll(m);
            }
        }
    }

    if (K > CAP) {  // pathological density: exact linear rescan (wave-uniform)
        linear_ball_fallback(xyz + (size_t)b * N * 3, cx, cy, cz, lane, lanemask_lt, out);
        return;
    }

    // Rank selection: rank(e) = #{candidates with smaller index}; indices unique.
    const int e0 = (lane < K) ? cand[lane] : 0x7FFFFFFF;
    const int e1 = (64 + lane < K) ? cand[64 + lane] : 0x7FFFFFFF;
    const int e2 = (128 + lane < K) ? cand[128 + lane] : 0x7FFFFFFF;
    int r0 = 0, r1 = 0, r2i = 0;
    if (K <= 64) {
        for (int k = 0; k < K; ++k) { const int v = cand[k]; r0 += (v < e0); }
    } else if (K <= 128) {
        for (int k = 0; k < K; ++k) { const int v = cand[k]; r0 += (v < e0); r1 += (v < e1); }
    } else {
        for (int k = 0; k < K; ++k) {
            const int v = cand[k];
            r0 += (v < e0); r1 += (v < e1); r2i += (v < e2);
        }
    }
    if (lane < K && r0 < NSAMPLE) out[r0] = e0;
    if (64 + lane < K && r1 < NSAMPLE) out[r1] = e1;
    if (128 + lane < K && r2i < NSAMPLE) out[r2i] = e2;

    if (K < NSAMPLE) {
        int mn = min(e0, min(e1, e2));
#pragma unroll
        for (int d = 32; d; d >>= 1) mn = min(mn, __shfl_xor(mn, d));
        const int fill = (K > 0) ? mn : 0;
        for (int pos = K + lane; pos < NSAMPLE; pos += 64) out[pos] = fill;
    }
}

// ---------------- Kernel 1: linear ball query (ws-too-small fallback) ----------------
__global__ void __launch_bounds__(256) ball_query_kernel(
    const float* __restrict__ xyz, const float* __restrict__ new_xyz,
    int* __restrict__ idx_out)
{
    const int wave = (blockIdx.x * blockDim.x + threadIdx.x) >> 6;
    const int lane = threadIdx.x & 63;
    if (wave >= B * NPOINT) return;
    const int b = wave / NPOINT;
    const float cx = new_xyz[(size_t)wave * 3 + 0];
    const float cy = new_xyz[(size_t)wave * 3 + 1];
    const float cz = new_xyz[(size_t)wave * 3 + 2];
    const unsigned long long lanemask_lt = (lane == 63) ? 0x7FFFFFFFFFFFFFFFull
                                                        : ((1ull << lane) - 1ull);
    linear_ball_fallback(xyz + (size_t)b * N * 3, cx, cy, cz, lane, lanemask_lt,
                         idx_out + (size_t)wave * NSAMPLE);
}

// ---------------- Kernel T: transpose features (B,C,N) -> (B,N,C) ----------------
__global__ void __launch_bounds__(256) transpose_kernel(
    const float* __restrict__ feat, float* __restrict__ ft) {
    __shared__ float tile[64 * 65];
    const int b = blockIdx.y;
    const int n0 = blockIdx.x * 64;
    const int t = threadIdx.x;
    const int l = t & 63;
    const int w = t >> 6;
#pragma unroll
    for (int it = 0; it < 16; ++it) {
        const int c = it * 4 + w;
        tile[c * 65 + l] = feat[((size_t)b * C + c) * N + n0 + l];
    }
    __syncthreads();
#pragma unroll
    for (int it = 0; it < 16; ++it) {
        const int nn = it * 4 + w;
        ft[((size_t)b * N + n0 + nn) * C + l] = tile[l * 65 + nn];
    }
}

// ---------------- Kernel 2: grouping, sorted queries + XCD swizzle ----------------
// 1D grid of B*NPOINT/2 blocks; swizzled so each XCD gets a contiguous sorted
// range (ft working set ~1 MB -> per-XCD L2-resident gathers).
__global__ void __launch_bounds__(256) group2_kernel(
    const float* __restrict__ xyz, const float* __restrict__ new_xyz,
    const float* __restrict__ ft, const int* __restrict__ idx_arr,
    const int* __restrict__ qperm, float* __restrict__ out) {
    __shared__ int sidx[64];
    __shared__ float sf[64 * 65];

    const int t = threadIdx.x;
    const int g = blockIdx.x;                       // 0 .. B*NPOINT/2-1 (4096)
    const int nwg = B * NPOINT / 2;
    const int swz = (g & 7) * (nwg / 8) + (g >> 3); // bijective: nwg % 8 == 0
    const int b = swz / (NPOINT / 2);
    const int p = swz - b * (NPOINT / 2);

    const int q0 = qperm[b * NPOINT + 2 * p + 0];   // broadcast loads
    const int q1 = qperm[b * NPOINT + 2 * p + 1];

    if (t < 64) {
        const int qq = (t < 32) ? q0 : q1;
        sidx[t] = idx_arr[((size_t)b * NPOINT + qq) * NSAMPLE + (t & 31)];
    }
    __syncthreads();

    // Phase 1: gather features. pair p <- 16 lanes, each lane one float4.
    {
        const int lane16 = t & 15;
        const int pq = t >> 4;
#pragma unroll
        for (int it = 0; it < 4; ++it) {
            const int pp = it * 16 + pq;
            const int id = sidx[pp];
            const float4 v = *(const float4*)(ft + ((size_t)b * N + id) * C + lane16 * 4);
            float* dst = sf + pp * 65 + lane16 * 4;
            dst[0] = v.x; dst[1] = v.y; dst[2] = v.z; dst[3] = v.w;
        }
    }

    const size_t plane = (size_t)NPOINT * NSAMPLE;
    const size_t bbase = (size_t)b * (3 + C) * plane;

    // xyz part: pair index = t (threads 0..63)
    if (t < 64) {
        const int id = sidx[t];
        const int qq = (t < 32) ? q0 : q1;
        const size_t cb = ((size_t)b * NPOINT + qq) * 3;
        const size_t pb = ((size_t)b * N + id) * 3;
        const size_t ob = bbase + (size_t)qq * NSAMPLE + (t & 31);
        {
#pragma clang fp contract(off)
            out[ob + 0 * plane] = xyz[pb + 0] - new_xyz[cb + 0];
            out[ob + 1 * plane] = xyz[pb + 1] - new_xyz[cb + 1];
            out[ob + 2 * plane] = xyz[pb + 2] - new_xyz[cb + 2];
        }
    }
    __syncthreads();

    // Phase 2: wave w writes channel c = it*4+w; lanes 0-31 -> q0 row, 32-63 -> q1 row.
    const int l = t & 63;
    const int w = t >> 6;
    const int qq = (l < 32) ? q0 : q1;
    const size_t rowbase = bbase + (size_t)qq * NSAMPLE + (l & 31);
#pragma unroll
    for (int it = 0; it < 16; ++it) {
        const int c = it * 4 + w;
        out[rowbase + (size_t)(3 + c) * plane] = sf[l * 65 + c];
    }
}

// ---------------- Fallback grouping (ws too small) ----------------
__global__ void __launch_bounds__(256) group_kernel(
    const float* __restrict__ xyz, const float* __restrict__ new_xyz,
    const float* __restrict__ feat, const int* __restrict__ idx_arr,
    float* __restrict__ out) {
    const int t = threadIdx.x;
    const int s = t & 31;
    const int jl = t >> 5;
    const int j = blockIdx.x * 8 + jl;
    const int b = blockIdx.y;

    const int id = idx_arr[((size_t)b * NPOINT + j) * NSAMPLE + s];

    const float px = xyz[((size_t)b * N + id) * 3 + 0] - new_xyz[((size_t)b * NPOINT + j) * 3 + 0];
    const float py = xyz[((size_t)b * N + id) * 3 + 1] - new_xyz[((size_t)b * NPOINT + j) * 3 + 1];
    const float pz = xyz[((size_t)b * N + id) * 3 + 2] - new_xyz[((size_t)b * NPOINT + j) * 3 + 2];

    const size_t plane = (size_t)NPOINT * NSAMPLE;
    const size_t obase = (size_t)b * (3 + C) * plane + (size_t)j * NSAMPLE + s;

    out[obase + 0 * plane] = px;
    out[obase + 1 * plane] = py;
    out[obase + 2 * plane] = pz;

    const float* __restrict__ fb = feat + (size_t)b * C * N;
#pragma unroll 8
    for (int c = 0; c < C; ++c) {
        out[obase + (size_t)(3 + c) * plane] = fb[(size_t)c * N + id];
    }
}

extern "C" void kernel_launch(void* const* d_in, const int* in_sizes, int n_in,
                              void* d_out, int out_size, void* d_ws, size_t ws_size,
                              hipStream_t stream) {
    const float* xyz     = (const float*)d_in[0];  // (B, N, 3)
    const float* new_xyz = (const float*)d_in[1];  // (B, NPOINT, 3)
    const float* feat    = (const float*)d_in[2];  // (B, C, N)
    float* out = (float*)d_out;

    // Workspace layout (contiguous)
    const size_t idx_bytes    = (size_t)B * NPOINT * NSAMPLE * sizeof(int);  // 1,048,576
    const size_t ft_bytes     = (size_t)B * N * C * sizeof(float);           // 8,388,608
    const size_t binned_bytes = (size_t)B * N * sizeof(float4);              //   524,288
    const size_t off_bytes    = (size_t)B * OFF_STRIDE * sizeof(int);        //     8,448
    const size_t cellw_bytes  = (size_t)B * CELLW_STRIDE * sizeof(int);      //     8,192
    const size_t qwork_bytes  = (size_t)B * CELLW_STRIDE * sizeof(int);      //     8,192
    const size_t qperm_bytes  = (size_t)B * NPOINT * sizeof(int);            //    32,768

    char* ws = (char*)d_ws;
    size_t o = 0;
    int*    idx_ws   = (int*)(ws + o);    o += idx_bytes;
    float*  ft       = (float*)(ws + o);  o += ft_bytes;
    float4* binned   = (float4*)(ws + o); o += binned_bytes;
    int*    off      = (int*)(ws + o);    o += off_bytes;
    int*    cellwork = (int*)(ws + o);    o += cellw_bytes;   // cellwork+qwork adjacent
    int*    qwork    = (int*)(ws + o);    o += qwork_bytes;
    int*    qperm    = (int*)(ws + o);    o += qperm_bytes;

    const bool use_grid = (ws_size >= o);

    if (use_grid) {
        transpose_kernel<<<dim3(N / 64, B), 256, 0, stream>>>(feat, ft);
        grid_init_kernel<<<(2 * B * CELLW_STRIDE + 255) / 256, 256, 0, stream>>>(cellwork);
        grid_hist_kernel<<<(B * (N + NPOINT) + 255) / 256, 256, 0, stream>>>(
            xyz, new_xyz, cellwork, qwork);
        grid_scan_kernel<<<2 * B, 1024, 0, stream>>>(cellwork, qwork, off);
        grid_scatter_kernel<<<(B * (N + NPOINT) + 255) / 256, 256, 0, stream>>>(
            xyz, new_xyz, cellwork, qwork, binned, qperm);
        ball_query_grid_kernel<<<(B * NPOINT) / 4, 256, 0, stream>>>(
            binned, off, new_xyz, xyz, qperm, idx_ws);
        group2_kernel<<<B * NPOINT / 2, 256, 0, stream>>>(
            xyz, new_xyz, ft, idx_ws, qperm, out);
    } else {
        ball_query_kernel<<<(B * NPOINT) / 4, 256, 0, stream>>>(xyz, new_xyz, idx_ws);
        dim3 grid2(NPOINT / 8, B);
        group_kernel<<<grid2, 256, 0, stream>>>(xyz, new_xyz, feat, idx_ws, out);
    }
}